// Round 1
// baseline (405.120 us; speedup 1.0000x reference)
//
#include <hip/hip_runtime.h>

#define PBIN 14
#define SSAMP 2
#define SCALE_F 0.0625f
#define TRANS_STD 0.1f
#define CCH 256
#define FCDIM 1024
#define NROIS 192
#define HH 128
#define WW 128
#define PP (PBIN*PBIN)      // 196
#define KDIM (CCH*PP)       // 50176

typedef __bf16 bf16x8 __attribute__((ext_vector_type(8)));
typedef float  f32x4  __attribute__((ext_vector_type(4)));
typedef unsigned u32x4 __attribute__((ext_vector_type(4)));

__device__ __forceinline__ unsigned short f2bf(float f) {
  unsigned u = __builtin_bit_cast(unsigned, f);
  u += 0x7FFFu + ((u >> 16) & 1u);   // RNE
  return (unsigned short)(u >> 16);
}

// pack two f32 -> one u32 holding (bf16(hi)<<16)|bf16(lo), round-half-up
__device__ __forceinline__ unsigned pk2(float lo, float hi) {
  unsigned ulo = __builtin_bit_cast(unsigned, lo) + 0x8000u;
  unsigned uhi = __builtin_bit_cast(unsigned, hi) + 0x8000u;
  return __builtin_amdgcn_perm(uhi, ulo, 0x07060302u); // [uhi.b3 uhi.b2 ulo.b3 ulo.b2]
}

// ---------------- transpose x [B,C,H,W] -> xt [B,H,W,C] ----------------
__global__ __launch_bounds__(256) void transpose_x_kernel(
    const float* __restrict__ x, float* __restrict__ xt)
{
  __shared__ float tile[32][33];
  int tx = threadIdx.x, ty = threadIdx.y;     // (32, 8)
  int hw0 = blockIdx.x * 32;
  int c0  = blockIdx.y * 32;
  int b   = blockIdx.z;
  const float* xb  = x  + (size_t)b * CCH * HH * WW;
  float*       xtb = xt + (size_t)b * CCH * HH * WW;
#pragma unroll
  for (int k = 0; k < 4; ++k)
    tile[ty + k*8][tx] = xb[(size_t)(c0 + ty + k*8) * (HH*WW) + hw0 + tx];
  __syncthreads();
#pragma unroll
  for (int k = 0; k < 4; ++k)
    xtb[(size_t)(hw0 + ty + k*8) * CCH + c0 + tx] = tile[tx][ty + k*8];
}

// ---------------- PSRoI pool (MODE 0: base->bf16, MODE 1: final*mask->f32) -----
template<int MODE>
__global__ __launch_bounds__(256) void pool_kernel(
    const float* __restrict__ xt, const float* __restrict__ rois,
    const float* __restrict__ om, void* __restrict__ outp)
{
  int p = threadIdx.x;
  if (p >= PP) return;
  int n = blockIdx.x;
  int cbase = blockIdx.y * 64;
  int ph = p / PBIN, pw = p % PBIN;

  float rb = rois[n*5 + 0];
  float x1 = rois[n*5 + 1], y1 = rois[n*5 + 2];
  float x2 = rois[n*5 + 3], y2 = rois[n*5 + 4];
  int b = (int)rb;
  float sw = rintf(x1) * SCALE_F - 0.5f;
  float sh = rintf(y1) * SCALE_F - 0.5f;
  float ew = (rintf(x2) + 1.0f) * SCALE_F - 0.5f;
  float eh = (rintf(y2) + 1.0f) * SCALE_F - 0.5f;
  float rw = fmaxf(ew - sw, 0.1f);
  float rh = fmaxf(eh - sh, 0.1f);
  float bw = rw / PBIN, bh = rh / PBIN;
  float subw = bw / SSAMP, subh = bh / SSAMP;

  float tx = 0.f, ty = 0.f, mval = 1.f;
  if (MODE == 1) {
    const float* omr = om + (size_t)n * (3*PP);
    tx = omr[p] * TRANS_STD;
    ty = omr[PP + p] * TRANS_STD;
    float z = omr[2*PP + p];
    mval = 1.0f / (1.0f + expf(-z));
  }
  float wstart = pw * bw + sw + tx * rw;
  float hstart = ph * bh + sh + ty * rh;

  int offs[16];
  float wts[16];
  float cnt = 0.f;
  int base_b = b * (HH*WW);
#pragma unroll
  for (int ih = 0; ih < SSAMP; ++ih) {
#pragma unroll
    for (int iw = 0; iw < SSAMP; ++iw) {
      float wv = wstart + iw * subw;
      float hv = hstart + ih * subh;
      float validf = (wv >= -0.5f && wv <= WW - 0.5f &&
                      hv >= -0.5f && hv <= HH - 0.5f) ? 1.f : 0.f;
      cnt += validf;
      float wc = fminf(fmaxf(wv, 0.f), WW - 1.0f);
      float hc = fminf(fmaxf(hv, 0.f), HH - 1.0f);
      int x0 = (int)floorf(wc), y0 = (int)floorf(hc);
      int x1i = min(x0 + 1, WW - 1), y1i = min(y0 + 1, HH - 1);
      float lx = wc - (float)x0, ly = hc - (float)y0;
      int s4 = (ih*2 + iw) * 4;
      offs[s4+0] = (base_b + y0 *WW + x0 ) * CCH + cbase;
      offs[s4+1] = (base_b + y0 *WW + x1i) * CCH + cbase;
      offs[s4+2] = (base_b + y1i*WW + x0 ) * CCH + cbase;
      offs[s4+3] = (base_b + y1i*WW + x1i) * CCH + cbase;
      wts[s4+0] = validf * (1.f-ly)*(1.f-lx);
      wts[s4+1] = validf * (1.f-ly)*lx;
      wts[s4+2] = validf * ly*(1.f-lx);
      wts[s4+3] = validf * ly*lx;
    }
  }
  float inv = 1.0f / fmaxf(cnt, 1.0f);
  if (MODE == 1) inv *= mval;

  for (int cc = 0; cc < 64; cc += 4) {
    f32x4 acc = {0.f, 0.f, 0.f, 0.f};
#pragma unroll
    for (int s = 0; s < 16; ++s) {
      f32x4 v = *(const f32x4*)&xt[offs[s] + cc];
      acc += wts[s] * v;
    }
    acc *= inv;
    size_t rowbase = (size_t)n * KDIM;
    if (MODE == 0) {
      unsigned short* bout = (unsigned short*)outp;
#pragma unroll
      for (int j = 0; j < 4; ++j)
        bout[rowbase + (size_t)(cbase + cc + j) * PP + p] = f2bf(acc[j]);
    } else {
      float* fout = (float*)outp;
#pragma unroll
      for (int j = 0; j < 4; ++j)
        fout[rowbase + (size_t)(cbase + cc + j) * PP + p] = acc[j];
    }
  }
}

// ---------------- split-K GEMM: C_partial[s] = A(bf16 192xK) * B(f32 KxN) ------
// BM=192 (full M), BN=128, BK=32, 8 waves (2m x 4n), wave tile 96x32.
__global__ __launch_bounds__(512) void gemm_splitk(
    const unsigned* __restrict__ A, int ldAu,        // A rows as u32 (bf16 pairs)
    const float* __restrict__ Bm, int N, int ldB,
    float* __restrict__ partial, int Kc)
{
  __shared__ __align__(16) unsigned lds_a[192*20];   // [m][16 u32 + pad4] stride 20
  __shared__ __align__(16) float    lds_b[32*133];   // [k][128 f32 + pad5] stride 133

  int t  = threadIdx.x;
  int n0 = blockIdx.x * 128;
  int s  = blockIdx.y;
  int k0 = s * Kc;

  int wv = t >> 6, lane = t & 63;
  int wm = wv & 1, wn = wv >> 1;                     // 2 x 4 waves
  int m0w = wm * 96;
  int n0w = wn * 32;
  int lrow = lane & 15, lg = lane >> 4;

  f32x4 acc[6][2];
#pragma unroll
  for (int i = 0; i < 6; ++i)
#pragma unroll
    for (int j = 0; j < 2; ++j) acc[i][j] = {0.f,0.f,0.f,0.f};

  for (int kk = 0; kk < Kc; kk += 32) {
    int kg = k0 + kk;
    // stage A: 192x32 bf16 = 3072 u32
#pragma unroll
    for (int i = 0; i < 6; ++i) {
      int u = t + i*512;
      int m = u >> 4, kp = u & 15;
      lds_a[m*20 + kp] = A[(size_t)m*ldAu + (kg>>1) + kp];
    }
    // stage B: 32x128 f32 (raw, converted at frag-read)
#pragma unroll
    for (int i = 0; i < 2; ++i) {
      int ft = t + i*512;
      int krow = ft >> 5, n4 = (ft & 31) * 4;
      int gn = n0 + n4;
      f32x4 v = {0.f,0.f,0.f,0.f};
      if (gn < N) v = *(const f32x4*)&Bm[(size_t)(kg + krow)*ldB + gn];
      float* dst = &lds_b[krow*133 + n4];
      dst[0] = v[0]; dst[1] = v[1]; dst[2] = v[2]; dst[3] = v[3];
    }
    __syncthreads();

    bf16x8 af[6];
#pragma unroll
    for (int mf = 0; mf < 6; ++mf) {
      u32x4 ra = *(const u32x4*)&lds_a[(m0w + mf*16 + lrow)*20 + lg*4];
      af[mf] = __builtin_bit_cast(bf16x8, ra);
    }
#pragma unroll
    for (int nf = 0; nf < 2; ++nf) {
      int col = n0w + nf*16 + lrow;
      int bidx = (lg*8)*133 + col;
      float bvv[8];
#pragma unroll
      for (int e = 0; e < 8; ++e) bvv[e] = lds_b[bidx + e*133];
      u32x4 ub = { pk2(bvv[0], bvv[1]), pk2(bvv[2], bvv[3]),
                   pk2(bvv[4], bvv[5]), pk2(bvv[6], bvv[7]) };
      bf16x8 bfr = __builtin_bit_cast(bf16x8, ub);
#pragma unroll
      for (int mf = 0; mf < 6; ++mf)
        acc[mf][nf] = __builtin_amdgcn_mfma_f32_16x16x32_bf16(af[mf], bfr, acc[mf][nf], 0, 0, 0);
    }
    __syncthreads();
  }

#pragma unroll
  for (int mf = 0; mf < 6; ++mf) {
#pragma unroll
    for (int nf = 0; nf < 2; ++nf) {
      int gcol = n0 + n0w + nf*16 + lrow;
      if (gcol < N) {
#pragma unroll
        for (int r = 0; r < 4; ++r) {
          int m = m0w + mf*16 + lg*4 + r;
          partial[((size_t)s*192 + m)*N + gcol] = acc[mf][nf][r];
        }
      }
    }
  }
}

// ---------------- reduce partials + bias + act, store bf16 or f32 -------------
__global__ __launch_bounds__(256) void reduce_kernel(
    const float* __restrict__ partial, const float* __restrict__ bias,
    void* __restrict__ outp, int N, int S, int act, int outBf16)
{
  int nn = blockIdx.x * 256 + threadIdx.x;
  int m  = blockIdx.y;
  if (nn >= N) return;
  float a = bias[nn];
  for (int s = 0; s < S; ++s)
    a += partial[((size_t)s*192 + m)*N + nn];
  if (act) a = fmaxf(a, 0.f);
  if (outBf16) ((unsigned short*)outp)[(size_t)m*N + nn] = f2bf(a);
  else         ((float*)outp)[(size_t)m*N + nn] = a;
}

extern "C" void kernel_launch(void* const* d_in, const int* in_sizes, int n_in,
                              void* d_out, int out_size, void* d_ws, size_t ws_size,
                              hipStream_t stream)
{
  const float* x    = (const float*)d_in[0];
  const float* rois = (const float*)d_in[1];
  const float* w1   = (const float*)d_in[2];
  const float* b1   = (const float*)d_in[3];
  const float* w2   = (const float*)d_in[4];
  const float* b2   = (const float*)d_in[5];
  const float* w3   = (const float*)d_in[6];
  const float* b3   = (const float*)d_in[7];

  char* ws = (char*)d_ws;
  size_t off = 0;
  float* xt = (float*)(ws + off);               off += (size_t)2*CCH*HH*WW*4;      // 33,554,432
  unsigned short* base = (unsigned short*)(ws + off); off += (size_t)NROIS*KDIM*2; // 19,267,584
  unsigned short* f1 = (unsigned short*)(ws + off);   off += (size_t)NROIS*FCDIM*2;
  unsigned short* f2 = (unsigned short*)(ws + off);   off += (size_t)NROIS*FCDIM*2;
  float* om = (float*)(ws + off);               off += (size_t)NROIS*3*PP*4;
  float* partial = (float*)(ws + off);
  size_t avail = (ws_size > off) ? (ws_size - off) : 0;

  // pick largest split count that fits (Kc must stay a multiple of 32)
  const int cand[9] = {49, 28, 16, 14, 8, 7, 4, 2, 1};
  int splits = 1;
  for (int i = 0; i < 9; ++i) {
    if ((size_t)cand[i]*NROIS*FCDIM*4 <= avail) { splits = cand[i]; break; }
  }
  int Kc1 = KDIM / splits;
  int splits2 = (splits >= 8) ? 8 : ((splits >= 4) ? 4 : splits);
  int Kc2 = FCDIM / splits2;

  // 1) transpose x -> xt
  transpose_x_kernel<<<dim3(512, 8, 2), dim3(32, 8), 0, stream>>>(x, xt);
  // 2) base pool -> bf16 [192, 50176]
  pool_kernel<0><<<dim3(NROIS, 4), 256, 0, stream>>>(xt, rois, nullptr, base);
  // 3) f1 = relu(base @ w1 + b1)
  gemm_splitk<<<dim3(8, splits), 512, 0, stream>>>((const unsigned*)base, KDIM/2, w1, FCDIM, FCDIM, partial, Kc1);
  reduce_kernel<<<dim3(4, NROIS), 256, 0, stream>>>(partial, b1, f1, FCDIM, splits, 1, 1);
  // 4) f2 = relu(f1 @ w2 + b2)
  gemm_splitk<<<dim3(8, splits2), 512, 0, stream>>>((const unsigned*)f1, FCDIM/2, w2, FCDIM, FCDIM, partial, Kc2);
  reduce_kernel<<<dim3(4, NROIS), 256, 0, stream>>>(partial, b2, f2, FCDIM, splits2, 1, 1);
  // 5) om = f2 @ w3 + b3   (N = 588)
  gemm_splitk<<<dim3(5, splits2), 512, 0, stream>>>((const unsigned*)f2, FCDIM/2, w3, 3*PP, 3*PP, partial, Kc2);
  reduce_kernel<<<dim3(3, NROIS), 256, 0, stream>>>(partial, b3, om, 3*PP, splits2, 0, 0);
  // 6) final pool with offsets, * sigmoid(mask) -> d_out
  pool_kernel<1><<<dim3(NROIS, 4), 256, 0, stream>>>(xt, rois, om, d_out);
}

// Round 2
// 215.893 us; speedup vs baseline: 1.8765x; 1.8765x over previous
//
#include <hip/hip_runtime.h>

#define PBIN 14
#define SSAMP 2
#define SCALE_F 0.0625f
#define TRANS_STD 0.1f
#define CCH 256
#define FCDIM 1024
#define NROIS 192
#define HH 128
#define WW 128
#define PP (PBIN*PBIN)      // 196
#define KDIM (CCH*PP)       // 50176

typedef __bf16 bf16x8 __attribute__((ext_vector_type(8)));
typedef float  f32x4  __attribute__((ext_vector_type(4)));
typedef unsigned u32x4 __attribute__((ext_vector_type(4)));
typedef unsigned u32x2 __attribute__((ext_vector_type(2)));

__device__ __forceinline__ unsigned short f2bf(float f) {
  unsigned u = __builtin_bit_cast(unsigned, f);
  u += 0x7FFFu + ((u >> 16) & 1u);   // RNE
  return (unsigned short)(u >> 16);
}

// pack two f32 -> one u32 holding (bf16(hi)<<16)|bf16(lo)
__device__ __forceinline__ unsigned pk2(float lo, float hi) {
  unsigned ulo = __builtin_bit_cast(unsigned, lo) + 0x8000u;
  unsigned uhi = __builtin_bit_cast(unsigned, hi) + 0x8000u;
  return __builtin_amdgcn_perm(uhi, ulo, 0x07060302u);
}

// ---------------- transpose x [B,C,H,W] -> xt [B,H,W,C] ----------------
__global__ __launch_bounds__(256) void transpose_x_kernel(
    const float* __restrict__ x, float* __restrict__ xt)
{
  __shared__ float tile[32][33];
  int tx = threadIdx.x, ty = threadIdx.y;     // (32, 8)
  int hw0 = blockIdx.x * 32;
  int c0  = blockIdx.y * 32;
  int b   = blockIdx.z;
  const float* xb  = x  + (size_t)b * CCH * HH * WW;
  float*       xtb = xt + (size_t)b * CCH * HH * WW;
#pragma unroll
  for (int k = 0; k < 4; ++k)
    tile[ty + k*8][tx] = xb[(size_t)(c0 + ty + k*8) * (HH*WW) + hw0 + tx];
  __syncthreads();
#pragma unroll
  for (int k = 0; k < 4; ++k)
    xtb[(size_t)(hw0 + ty + k*8) * CCH + c0 + tx] = tile[tx][ty + k*8];
}

// ---------------- PSRoI pool: wave = bin, lane = channel-quad -----------------
// MODE 0: base -> bf16 [n][p*256+c] (coalesced). MODE 1: final*mask -> f32 [n][c][p].
template<int MODE>
__global__ __launch_bounds__(256) void pool_kernel(
    const float* __restrict__ xt, const float* __restrict__ rois,
    const float* __restrict__ om, void* __restrict__ outp)
{
  __shared__ float lds[4][256];
  const int t = threadIdx.x;
  const int wv = t >> 6, lane = t & 63;
  const int n  = blockIdx.x;
  const int p0 = blockIdx.y * 4;
  const int p  = p0 + wv;                     // 49*4 = 196 bins
  const int ph = p / PBIN, pw = p % PBIN;

  float rb = rois[n*5 + 0];
  float x1 = rois[n*5 + 1], y1 = rois[n*5 + 2];
  float x2 = rois[n*5 + 3], y2 = rois[n*5 + 4];
  int b = (int)rb;
  float sw = rintf(x1) * SCALE_F - 0.5f;
  float sh = rintf(y1) * SCALE_F - 0.5f;
  float ew = (rintf(x2) + 1.0f) * SCALE_F - 0.5f;
  float eh = (rintf(y2) + 1.0f) * SCALE_F - 0.5f;
  float rw = fmaxf(ew - sw, 0.1f);
  float rh = fmaxf(eh - sh, 0.1f);
  float bw = rw / PBIN, bh = rh / PBIN;
  float subw = bw / SSAMP, subh = bh / SSAMP;

  float tx = 0.f, ty = 0.f, mval = 1.f;
  if (MODE == 1) {
    const float* omr = om + (size_t)n * (3*PP);
    tx = omr[p] * TRANS_STD;
    ty = omr[PP + p] * TRANS_STD;
    float z = omr[2*PP + p];
    mval = 1.0f / (1.0f + expf(-z));
  }
  float wstart = pw * bw + sw + tx * rw;
  float hstart = ph * bh + sh + ty * rh;

  int offs[16];
  float wts[16];
  float cnt = 0.f;
  int base_b = b * (HH*WW);
#pragma unroll
  for (int ih = 0; ih < SSAMP; ++ih) {
#pragma unroll
    for (int iw = 0; iw < SSAMP; ++iw) {
      float wv_ = wstart + iw * subw;
      float hv_ = hstart + ih * subh;
      float validf = (wv_ >= -0.5f && wv_ <= WW - 0.5f &&
                      hv_ >= -0.5f && hv_ <= HH - 0.5f) ? 1.f : 0.f;
      cnt += validf;
      float wc = fminf(fmaxf(wv_, 0.f), WW - 1.0f);
      float hc = fminf(fmaxf(hv_, 0.f), HH - 1.0f);
      int x0 = (int)floorf(wc), y0 = (int)floorf(hc);
      int x1i = min(x0 + 1, WW - 1), y1i = min(y0 + 1, HH - 1);
      float lx = wc - (float)x0, ly = hc - (float)y0;
      int s4 = (ih*2 + iw) * 4;
      offs[s4+0] = (base_b + y0 *WW + x0 ) * CCH;
      offs[s4+1] = (base_b + y0 *WW + x1i) * CCH;
      offs[s4+2] = (base_b + y1i*WW + x0 ) * CCH;
      offs[s4+3] = (base_b + y1i*WW + x1i) * CCH;
      wts[s4+0] = validf * (1.f-ly)*(1.f-lx);
      wts[s4+1] = validf * (1.f-ly)*lx;
      wts[s4+2] = validf * ly*(1.f-lx);
      wts[s4+3] = validf * ly*lx;
    }
  }
  float inv = 1.0f / fmaxf(cnt, 1.0f);
  if (MODE == 1) inv *= mval;

  const int cl = lane * 4;
  f32x4 acc = {0.f, 0.f, 0.f, 0.f};
#pragma unroll
  for (int s = 0; s < 16; ++s) {
    f32x4 v = *(const f32x4*)&xt[offs[s] + cl];
    acc += wts[s] * v;
  }
  acc *= inv;

  if (MODE == 0) {
    unsigned short* bout = (unsigned short*)outp;
    u32x2 pkd = { pk2(acc[0], acc[1]), pk2(acc[2], acc[3]) };
    *(u32x2*)&bout[(size_t)n*KDIM + p*CCH + cl] = pkd;   // coalesced 8B/lane
  } else {
    *(f32x4*)&lds[wv][cl] = acc;
    __syncthreads();
    float* fout = (float*)outp;
    int c = t;                                            // 256 channels
    f32x4 o = { lds[0][c], lds[1][c], lds[2][c], lds[3][c] };
    *(f32x4*)&fout[(size_t)n*KDIM + (size_t)c*PP + p0] = o; // 16B/lane
  }
}

// ---------------- split-K GEMM: C_partial[s] = A(bf16 192xK) * B(f32 KxN) ------
// BM=192 (full M), BN=128, BK=32, 8 waves (2m x 4n), wave tile 96x32.
// PERM=1: A's k-index is p*256+c; map B row r -> w1 row (r&255)*196 + (r>>8).
template<int PERM>
__global__ __launch_bounds__(512) void gemm_splitk(
    const unsigned* __restrict__ A, int ldAu,        // A rows as u32 (bf16 pairs)
    const float* __restrict__ Bm, int N, int ldB,
    float* __restrict__ partial, int Kc)
{
  __shared__ __align__(16) unsigned lds_a[192*20];   // [m][16 u32 + pad4] stride 20
  __shared__ __align__(16) float    lds_b[32*133];   // [k][128 f32 + pad5] stride 133

  int t  = threadIdx.x;
  int n0 = blockIdx.x * 128;
  int s  = blockIdx.y;
  int k0 = s * Kc;

  int wv = t >> 6, lane = t & 63;
  int wm = wv & 1, wn = wv >> 1;                     // 2 x 4 waves
  int m0w = wm * 96;
  int n0w = wn * 32;
  int lrow = lane & 15, lg = lane >> 4;

  f32x4 acc[6][2];
#pragma unroll
  for (int i = 0; i < 6; ++i)
#pragma unroll
    for (int j = 0; j < 2; ++j) acc[i][j] = {0.f,0.f,0.f,0.f};

  for (int kk = 0; kk < Kc; kk += 32) {
    int kg = k0 + kk;
    // stage A: 192x32 bf16 = 3072 u32
#pragma unroll
    for (int i = 0; i < 6; ++i) {
      int u = t + i*512;
      int m = u >> 4, kp = u & 15;
      lds_a[m*20 + kp] = A[(size_t)m*ldAu + (kg>>1) + kp];
    }
    // stage B: 32x128 f32 (raw, converted at frag-read)
#pragma unroll
    for (int i = 0; i < 2; ++i) {
      int ft = t + i*512;
      int krow = ft >> 5, n4 = (ft & 31) * 4;
      int gn = n0 + n4;
      int r = kg + krow;
      size_t srow = PERM ? ((size_t)(r & 255) * PP + (r >> 8)) : (size_t)r;
      f32x4 v = {0.f,0.f,0.f,0.f};
      if (gn < N) v = *(const f32x4*)&Bm[srow*ldB + gn];
      float* dst = &lds_b[krow*133 + n4];
      dst[0] = v[0]; dst[1] = v[1]; dst[2] = v[2]; dst[3] = v[3];
    }
    __syncthreads();

    bf16x8 af[6];
#pragma unroll
    for (int mf = 0; mf < 6; ++mf) {
      u32x4 ra = *(const u32x4*)&lds_a[(m0w + mf*16 + lrow)*20 + lg*4];
      af[mf] = __builtin_bit_cast(bf16x8, ra);
    }
#pragma unroll
    for (int nf = 0; nf < 2; ++nf) {
      int col = n0w + nf*16 + lrow;
      int bidx = (lg*8)*133 + col;
      float bvv[8];
#pragma unroll
      for (int e = 0; e < 8; ++e) bvv[e] = lds_b[bidx + e*133];
      u32x4 ub = { pk2(bvv[0], bvv[1]), pk2(bvv[2], bvv[3]),
                   pk2(bvv[4], bvv[5]), pk2(bvv[6], bvv[7]) };
      bf16x8 bfr = __builtin_bit_cast(bf16x8, ub);
#pragma unroll
      for (int mf = 0; mf < 6; ++mf)
        acc[mf][nf] = __builtin_amdgcn_mfma_f32_16x16x32_bf16(af[mf], bfr, acc[mf][nf], 0, 0, 0);
    }
    __syncthreads();
  }

#pragma unroll
  for (int mf = 0; mf < 6; ++mf) {
#pragma unroll
    for (int nf = 0; nf < 2; ++nf) {
      int gcol = n0 + n0w + nf*16 + lrow;
      if (gcol < N) {
#pragma unroll
        for (int r = 0; r < 4; ++r) {
          int m = m0w + mf*16 + lg*4 + r;
          partial[((size_t)s*192 + m)*N + gcol] = acc[mf][nf][r];
        }
      }
    }
  }
}

// ---------------- reduce partials + bias + act, store bf16 or f32 -------------
__global__ __launch_bounds__(256) void reduce_kernel(
    const float* __restrict__ partial, const float* __restrict__ bias,
    void* __restrict__ outp, int N, int S, int act, int outBf16)
{
  int nn = blockIdx.x * 256 + threadIdx.x;
  int m  = blockIdx.y;
  if (nn >= N) return;
  float a = bias[nn];
  for (int s = 0; s < S; ++s)
    a += partial[((size_t)s*192 + m)*N + nn];
  if (act) a = fmaxf(a, 0.f);
  if (outBf16) ((unsigned short*)outp)[(size_t)m*N + nn] = f2bf(a);
  else         ((float*)outp)[(size_t)m*N + nn] = a;
}

extern "C" void kernel_launch(void* const* d_in, const int* in_sizes, int n_in,
                              void* d_out, int out_size, void* d_ws, size_t ws_size,
                              hipStream_t stream)
{
  const float* x    = (const float*)d_in[0];
  const float* rois = (const float*)d_in[1];
  const float* w1   = (const float*)d_in[2];
  const float* b1   = (const float*)d_in[3];
  const float* w2   = (const float*)d_in[4];
  const float* b2   = (const float*)d_in[5];
  const float* w3   = (const float*)d_in[6];
  const float* b3   = (const float*)d_in[7];

  char* ws = (char*)d_ws;
  size_t off = 0;
  float* xt = (float*)(ws + off);               off += (size_t)2*CCH*HH*WW*4;
  unsigned short* base = (unsigned short*)(ws + off); off += (size_t)NROIS*KDIM*2;
  unsigned short* f1 = (unsigned short*)(ws + off);   off += (size_t)NROIS*FCDIM*2;
  unsigned short* f2 = (unsigned short*)(ws + off);   off += (size_t)NROIS*FCDIM*2;
  float* om = (float*)(ws + off);               off += (size_t)NROIS*3*PP*4;
  float* partial = (float*)(ws + off);
  size_t avail = (ws_size > off) ? (ws_size - off) : 0;

  const int cand[9] = {49, 28, 16, 14, 8, 7, 4, 2, 1};
  int splits = 1;
  for (int i = 0; i < 9; ++i) {
    if ((size_t)cand[i]*NROIS*FCDIM*4 <= avail) { splits = cand[i]; break; }
  }
  int Kc1 = KDIM / splits;
  int splits2 = (splits >= 8) ? 8 : ((splits >= 4) ? 4 : splits);
  int Kc2 = FCDIM / splits2;

  // 1) transpose x -> xt
  transpose_x_kernel<<<dim3(512, 8, 2), dim3(32, 8), 0, stream>>>(x, xt);
  // 2) base pool -> bf16 [192, 50176] (k = p*256+c layout)
  pool_kernel<0><<<dim3(NROIS, PP/4), 256, 0, stream>>>(xt, rois, nullptr, base);
  // 3) f1 = relu(base @ w1 + b1)  (w1 rows permuted to match A's k layout)
  gemm_splitk<1><<<dim3(8, splits), 512, 0, stream>>>((const unsigned*)base, KDIM/2, w1, FCDIM, FCDIM, partial, Kc1);
  reduce_kernel<<<dim3(4, NROIS), 256, 0, stream>>>(partial, b1, f1, FCDIM, splits, 1, 1);
  // 4) f2 = relu(f1 @ w2 + b2)
  gemm_splitk<0><<<dim3(8, splits2), 512, 0, stream>>>((const unsigned*)f1, FCDIM/2, w2, FCDIM, FCDIM, partial, Kc2);
  reduce_kernel<<<dim3(4, NROIS), 256, 0, stream>>>(partial, b2, f2, FCDIM, splits2, 1, 1);
  // 5) om = f2 @ w3 + b3   (N = 588)
  gemm_splitk<0><<<dim3(5, splits2), 512, 0, stream>>>((const unsigned*)f2, FCDIM/2, w3, 3*PP, 3*PP, partial, Kc2);
  reduce_kernel<<<dim3(3, NROIS), 256, 0, stream>>>(partial, b3, om, 3*PP, splits2, 0, 0);
  // 6) final pool with offsets, * sigmoid(mask) -> d_out
  pool_kernel<1><<<dim3(NROIS, PP/4), 256, 0, stream>>>(xt, rois, om, d_out);
}